// Round 1
// baseline (992.100 us; speedup 1.0000x reference)
//
#include <hip/hip_runtime.h>
#include <stdint.h>

#define E_NUM 8
#define CAP 8192
#define NTOK 32768
#define CDIM 384
#define DFF 1536

typedef unsigned short u16;
typedef __attribute__((ext_vector_type(8))) short short8;
typedef __attribute__((ext_vector_type(4))) float f32x4;

__device__ inline u16 f2bf(float f) {
    uint32_t u = __builtin_bit_cast(uint32_t, f);
    u += 0x7fffu + ((u >> 16) & 1u);
    return (u16)(u >> 16);
}

__device__ inline void gload_lds16(const void* g, void* l) {
    __builtin_amdgcn_global_load_lds(
        (const __attribute__((address_space(1))) void*)(uintptr_t)g,
        (__attribute__((address_space(3))) void*)(uint32_t)(uintptr_t)l,
        16, 0, 0);
}

// ---------------- routing: 1 wave per token ----------------
__global__ __launch_bounds__(256) void routing_kernel(
    const float* __restrict__ x, const float* __restrict__ noise,
    const float* __restrict__ w_route, const float* __restrict__ b_route,
    const float* __restrict__ w_noise, const float* __restrict__ b_noise,
    int* __restrict__ cnt, int* __restrict__ list, float* __restrict__ gate)
{
    int w = threadIdx.x >> 6, lane = threadIdx.x & 63;
    int t = blockIdx.x * 4 + w;
    const float* xr = x + (size_t)t * CDIM;
    float ar[E_NUM], an[E_NUM];
#pragma unroll
    for (int e = 0; e < E_NUM; ++e) { ar[e] = 0.f; an[e] = 0.f; }
#pragma unroll
    for (int i = 0; i < CDIM / 64; ++i) {
        int c = lane + i * 64;
        float xv = xr[c];
        const float* wr = w_route + c * E_NUM;
        const float* wn = w_noise + c * E_NUM;
#pragma unroll
        for (int e = 0; e < E_NUM; ++e) {
            ar[e] += xv * wr[e];
            an[e] += xv * wn[e];
        }
    }
#pragma unroll
    for (int e = 0; e < E_NUM; ++e) {
#pragma unroll
        for (int off = 32; off > 0; off >>= 1) {
            ar[e] += __shfl_xor(ar[e], off);
            an[e] += __shfl_xor(an[e], off);
        }
    }
    if (lane == 0) {
        float nz[E_NUM];
#pragma unroll
        for (int e = 0; e < E_NUM; ++e) {
            float lg = ar[e] + b_route[e];
            float nl = an[e] + b_noise[e];
            float sp = fmaxf(nl, 0.f) + log1pf(expf(-fabsf(nl)));  // stable softplus
            nz[e] = lg + noise[(size_t)t * E_NUM + e] * sp;
        }
        float v1 = -1e30f; int i1 = 0;
#pragma unroll
        for (int e = 0; e < E_NUM; ++e) if (nz[e] > v1) { v1 = nz[e]; i1 = e; }
        float v2 = -1e30f;
#pragma unroll
        for (int e = 0; e < E_NUM; ++e) if (e != i1 && nz[e] > v2) v2 = nz[e];
        float g = 1.f / (1.f + expf(v2 - v1));
        gate[t] = g;
        int pos = atomicAdd(&cnt[i1], 1);
        if (pos < CAP) list[i1 * CAP + pos] = t;
    }
}

// ------------- transpose + fp32->bf16 convert: in (R,S) -> out (S,R) -------------
__global__ __launch_bounds__(256) void transpose_cvt_kernel(
    const float* __restrict__ in, u16* __restrict__ out, int R, int S)
{
    __shared__ float tile[32][33];
    size_t eoff = (size_t)blockIdx.z * R * S;
    const float* ip = in + eoff;
    u16* op = out + eoff;
    int c0 = blockIdx.x * 32, r0 = blockIdx.y * 32;
    int tx = threadIdx.x, ty = threadIdx.y;
#pragma unroll
    for (int i = ty; i < 32; i += 8)
        tile[i][tx] = ip[(size_t)(r0 + i) * S + (c0 + tx)];
    __syncthreads();
#pragma unroll
    for (int i = ty; i < 32; i += 8)
        op[(size_t)(c0 + i) * R + (r0 + tx)] = f2bf(tile[tx][i]);
}

// ------------- gather x rows -> bf16, zero-pad to 128 boundary -------------
__global__ __launch_bounds__(256) void gather_kernel(
    const float* __restrict__ x, const int* __restrict__ list,
    const int* __restrict__ cnt, u16* __restrict__ Xg,
    int list_stride, int cnt_stride, size_t xg_stride)
{
    int e = blockIdx.z;
    const int* le = list + (size_t)e * list_stride;
    int n = min(cnt[e * cnt_stride], CAP);
    u16* xg = Xg + (size_t)e * xg_stride;
    int w = threadIdx.x >> 6, lane = threadIdx.x & 63;
    int row = blockIdx.x * 4 + w;
    int pad = (n + 127) & ~127;
    if (row >= pad) return;
    u16* orow = xg + (size_t)row * CDIM;
    if (row < n) {
        const float* xr = x + (size_t)le[row] * CDIM;
#pragma unroll
        for (int i = 0; i < CDIM / 64; ++i) orow[lane + i * 64] = f2bf(xr[lane + i * 64]);
    } else {
#pragma unroll
        for (int i = 0; i < CDIM / 64; ++i) orow[lane + i * 64] = 0;
    }
}

// ------------- bf16 MFMA GEMM, 128x128 tile, m97 structure -------------
// A: M x KD bf16 row-major (lda=KD). Bt: ND x KD bf16 row-major (B transposed).
// FFN1: H[row*ND+col] = bf16(relu(acc+b1[col])^2)
// FFN2: Out[tok*CDIM+col] = (acc+b2[col]) * gate[tok], tok = list[row]
template <int KD, int ND, bool FFN1>
__global__ __launch_bounds__(256) void gemm_kernel(
    const u16* __restrict__ A, size_t a_estride,
    const u16* __restrict__ Bt, size_t b_estride,
    const float* __restrict__ bias, int bias_estride,
    u16* __restrict__ H, size_t h_estride,
    float* __restrict__ Out,
    const int* __restrict__ cnt, int cnt_stride,
    const int* __restrict__ list, int list_stride,
    const float* __restrict__ gate)
{
    int e = blockIdx.z;
    int n_e = min(cnt[e * cnt_stride], CAP);
    int m0 = blockIdx.y * 128;
    if (m0 >= n_e) return;
    const u16* Ae = A + (size_t)e * a_estride;
    const u16* Be = Bt + (size_t)e * b_estride;

    __shared__ __align__(16) u16 As[128 * 32];
    __shared__ __align__(16) u16 Bs[128 * 32];

    int tid = threadIdx.x;
    int w = tid >> 6, lane = tid & 63;
    int quad = lane >> 4, l15 = lane & 15;
    int wr = w & 1, wc = w >> 1;
    int n0 = blockIdx.x * 128;

    f32x4 acc[4][4];
    f32x4 zero = {0.f, 0.f, 0.f, 0.f};
#pragma unroll
    for (int a = 0; a < 4; ++a)
#pragma unroll
        for (int b = 0; b < 4; ++b) acc[a][b] = zero;

    for (int kb = 0; kb < KD / 32; ++kb) {
#pragma unroll
        for (int i = 0; i < 2; ++i) {
            int sb = i * 256 + w * 64;
            int sl = sb + lane;
            int row = sl >> 2, ks = sl & 3;
            gload_lds16(Ae + (size_t)(m0 + row) * KD + kb * 32 + ks * 8, &As[sb * 8]);
            gload_lds16(Be + (size_t)(n0 + row) * KD + kb * 32 + ks * 8, &Bs[sb * 8]);
        }
        __syncthreads();
        short8 af[4], bf[4];
#pragma unroll
        for (int t = 0; t < 4; ++t) {
            af[t] = *(const short8*)&As[(wr * 64 + t * 16 + l15) * 32 + quad * 8];
            bf[t] = *(const short8*)&Bs[(wc * 64 + t * 16 + l15) * 32 + quad * 8];
        }
#pragma unroll
        for (int mt = 0; mt < 4; ++mt)
#pragma unroll
            for (int nt = 0; nt < 4; ++nt)
                acc[mt][nt] = __builtin_amdgcn_mfma_f32_16x16x32_bf16(
                    af[mt], bf[nt], acc[mt][nt], 0, 0, 0);
        __syncthreads();
    }

    if (FFN1) {
        u16* He = H + (size_t)e * h_estride;
#pragma unroll
        for (int mt = 0; mt < 4; ++mt) {
            int row = m0 + wr * 64 + mt * 16 + quad * 4;
#pragma unroll
            for (int nt = 0; nt < 4; ++nt) {
                int col = n0 + wc * 64 + nt * 16 + l15;
                float b = bias[e * bias_estride + col];
#pragma unroll
                for (int r = 0; r < 4; ++r) {
                    float v = acc[mt][nt][r] + b;
                    v = fmaxf(v, 0.f);
                    v = v * v;
                    He[(size_t)(row + r) * ND + col] = f2bf(v);
                }
            }
        }
    } else {
#pragma unroll
        for (int mt = 0; mt < 4; ++mt) {
            int row = m0 + wr * 64 + mt * 16 + quad * 4;
#pragma unroll
            for (int r = 0; r < 4; ++r) {
                int rr = row + r;
                if (rr < n_e) {
                    int tok = list[e * list_stride + rr];
                    float g = gate[tok];
#pragma unroll
                    for (int nt = 0; nt < 4; ++nt) {
                        int col = n0 + wc * 64 + nt * 16 + l15;
                        float v = acc[mt][nt][r] + bias[e * bias_estride + col];
                        Out[(size_t)tok * CDIM + col] = v * g;
                    }
                }
            }
        }
    }
}

extern "C" void kernel_launch(void* const* d_in, const int* in_sizes, int n_in,
                              void* d_out, int out_size, void* d_ws, size_t ws_size,
                              hipStream_t stream)
{
    const float* x       = (const float*)d_in[0];
    const float* noise   = (const float*)d_in[1];
    const float* w_route = (const float*)d_in[2];
    const float* b_route = (const float*)d_in[3];
    const float* w_noise = (const float*)d_in[4];
    const float* b_noise = (const float*)d_in[5];
    const float* w1      = (const float*)d_in[6];
    const float* b1      = (const float*)d_in[7];
    const float* w2      = (const float*)d_in[8];
    const float* b2      = (const float*)d_in[9];
    float* out = (float*)d_out;

    char* ws = (char*)d_ws;
    size_t off = 0;
    auto alloc = [&](size_t bytes) {
        char* p = ws + off;
        off += (bytes + 255) & ~(size_t)255;
        return p;
    };
    int*   cnt  = (int*)alloc(E_NUM * sizeof(int));
    int*   list = (int*)alloc((size_t)E_NUM * CAP * sizeof(int));
    float* gate = (float*)alloc((size_t)NTOK * sizeof(float));
    u16*   W1t  = (u16*)alloc((size_t)E_NUM * DFF * CDIM * 2);
    u16*   W2t  = (u16*)alloc((size_t)E_NUM * CDIM * DFF * 2);

    size_t xg_full = (size_t)E_NUM * CAP * CDIM * 2;
    size_t h_full  = (size_t)E_NUM * CAP * DFF * 2;
    size_t xg_one  = (size_t)CAP * CDIM * 2;
    size_t h_one   = (size_t)CAP * DFF * 2;
    bool full = (ws_size > off) && (ws_size - off >= xg_full + h_full + 1024);

    hipMemsetAsync(cnt, 0, E_NUM * sizeof(int), stream);
    hipMemsetAsync(d_out, 0, (size_t)out_size * sizeof(float), stream);

    routing_kernel<<<NTOK / 4, 256, 0, stream>>>(x, noise, w_route, b_route,
                                                 w_noise, b_noise, cnt, list, gate);
    // w1[e]: (C, DFF) -> W1t[e]: (DFF, C)
    transpose_cvt_kernel<<<dim3(DFF / 32, CDIM / 32, E_NUM), dim3(32, 8), 0, stream>>>(
        w1, W1t, CDIM, DFF);
    // w2[e]: (DFF, C) -> W2t[e]: (C, DFF)
    transpose_cvt_kernel<<<dim3(CDIM / 32, DFF / 32, E_NUM), dim3(32, 8), 0, stream>>>(
        w2, W2t, DFF, CDIM);

    if (full) {
        u16* Xg = (u16*)alloc(xg_full);
        u16* Hb = (u16*)alloc(h_full);
        gather_kernel<<<dim3(CAP / 4, 1, E_NUM), 256, 0, stream>>>(
            x, list, cnt, Xg, CAP, 1, (size_t)CAP * CDIM);
        gemm_kernel<CDIM, DFF, true><<<dim3(DFF / 128, CAP / 128, E_NUM), 256, 0, stream>>>(
            Xg, (size_t)CAP * CDIM, W1t, (size_t)DFF * CDIM, b1, DFF,
            Hb, (size_t)CAP * DFF, nullptr, cnt, 1, nullptr, 0, nullptr);
        gemm_kernel<DFF, CDIM, false><<<dim3(CDIM / 128, CAP / 128, E_NUM), 256, 0, stream>>>(
            Hb, (size_t)CAP * DFF, W2t, (size_t)CDIM * DFF, b2, CDIM,
            nullptr, 0, out, cnt, 1, list, CAP, gate);
    } else {
        u16* Xg = (u16*)alloc(xg_one);
        u16* Hb = (u16*)alloc(h_one);
        for (int e = 0; e < E_NUM; ++e) {
            gather_kernel<<<dim3(CAP / 4, 1, 1), 256, 0, stream>>>(
                x, list + (size_t)e * CAP, cnt + e, Xg, 0, 0, 0);
            gemm_kernel<CDIM, DFF, true><<<dim3(DFF / 128, CAP / 128, 1), 256, 0, stream>>>(
                Xg, 0, W1t + (size_t)e * DFF * CDIM, 0, b1 + (size_t)e * DFF, 0,
                Hb, 0, nullptr, cnt + e, 0, nullptr, 0, nullptr);
            gemm_kernel<DFF, CDIM, false><<<dim3(CDIM / 128, CAP / 128, 1), 256, 0, stream>>>(
                Hb, 0, W2t + (size_t)e * CDIM * DFF, 0, b2 + (size_t)e * CDIM, 0,
                nullptr, 0, out, cnt + e, 0, list + (size_t)e * CAP, 0, gate);
        }
    }
}